// Round 1
// baseline (180.334 us; speedup 1.0000x reference)
//
#include <hip/hip_runtime.h>
#include <hip/hip_fp16.h>

#define Bdim 8
#define Nn   2048
#define Ff   64
#define Uu   64
#define Rr   16          // rows per block
#define NT   256

typedef _Float16 f16x8 __attribute__((ext_vector_type(8)));
typedef float    f32x4 __attribute__((ext_vector_type(4)));

__global__ __launch_bounds__(NT) void fused_gcn(
    const float* __restrict__ X,      // [B,N,F]
    const float* __restrict__ Dyn,    // [B,N,N]
    const float* __restrict__ Wf,     // [B,N,N,3]
    const float* __restrict__ Geo,    // [N,N]
    const float* __restrict__ KLm,    // [N,N]
    const float* __restrict__ Wd,     // [F,U]
    const float* __restrict__ bdv,    // [U]
    float* __restrict__ out)          // [B,N,U]
{
    // exp(fusion) rows, f16, XOR-swizzled rows of 2048 (64 KB)
    __shared__ __align__(16) _Float16 fus[Rr * Nn];
    __shared__ float wavesum[Rr][4];
    __shared__ float inv_rowsum[Rr];

    const int t  = threadIdx.x;
    const int b  = blockIdx.x >> 7;            // 128 blocks per batch
    const int n0 = (blockIdx.x & 127) << 4;    // 16 rows per block
    char* fb = (char*)fus;

    // ================= Phase 1: fusion + exp, f16 to LDS, row sums ========
    const size_t rowbase = ((size_t)b * Nn + n0) * Nn;
    const int m0 = t * 8;                      // 8 consecutive m per thread

    for (int r = 0; r < Rr; ++r) {
        const float* dp = Dyn + rowbase + (size_t)r * Nn + m0;
        const float* wp = Wf  + (rowbase + (size_t)r * Nn + m0) * 3;
        const float* gp = Geo + (size_t)(n0 + r) * Nn + m0;
        const float* kp = KLm + (size_t)(n0 + r) * Nn + m0;

        float4 d_a = ((const float4*)dp)[0];
        float4 d_b = ((const float4*)dp)[1];
        float4 w_0 = ((const float4*)wp)[0];
        float4 w_1 = ((const float4*)wp)[1];
        float4 w_2 = ((const float4*)wp)[2];
        float4 w_3 = ((const float4*)wp)[3];
        float4 w_4 = ((const float4*)wp)[4];
        float4 w_5 = ((const float4*)wp)[5];
        float4 g_a = ((const float4*)gp)[0];
        float4 g_b = ((const float4*)gp)[1];
        float4 k_a = ((const float4*)kp)[0];
        float4 k_b = ((const float4*)kp)[1];

        float dv[8] = {d_a.x,d_a.y,d_a.z,d_a.w, d_b.x,d_b.y,d_b.z,d_b.w};
        float gv[8] = {g_a.x,g_a.y,g_a.z,g_a.w, g_b.x,g_b.y,g_b.z,g_b.w};
        float kv[8] = {k_a.x,k_a.y,k_a.z,k_a.w, k_b.x,k_b.y,k_b.z,k_b.w};
        float wv[24] = {w_0.x,w_0.y,w_0.z,w_0.w,
                        w_1.x,w_1.y,w_1.z,w_1.w,
                        w_2.x,w_2.y,w_2.z,w_2.w,
                        w_3.x,w_3.y,w_3.z,w_3.w,
                        w_4.x,w_4.y,w_4.z,w_4.w,
                        w_5.x,w_5.y,w_5.z,w_5.w};

        f16x8 hv;
        float psum = 0.f;
        #pragma unroll
        for (int j = 0; j < 8; ++j) {
            float fu = dv[j]*wv[3*j] + gv[j]*wv[3*j+1] + kv[j]*wv[3*j+2];
            float e  = __expf(fminf(fu, 11.0f));   // inf-safety, never hit in practice
            _Float16 h = (_Float16)e;
            hv[j] = h;
            psum += (float)h;                      // sum the stored (rounded) value
        }
        // contiguous b128 write, row-XOR swizzle (free on write: uniform per wave)
        *(f16x8*)(fb + ((r * (Nn*2) + m0*2) ^ ((r & 7) << 4))) = hv;

        #pragma unroll
        for (int off = 32; off > 0; off >>= 1)
            psum += __shfl_down(psum, off, 64);
        if ((t & 63) == 0) wavesum[r][t >> 6] = psum;
    }
    __syncthreads();
    if (t < Rr)
        inv_rowsum[t] = 1.0f / (wavesum[t][0] + wavesum[t][1] +
                                wavesum[t][2] + wavesum[t][3]);

    // ================= Phase 2: MFMA  P(f16) @ X(f16) -> G1 ===============
    const int lane = t & 63, wid = t >> 6;
    const int arow = lane & 15;        // A row / C col index
    const int kg   = lane >> 4;        // k-group
    const int fcol = wid * 16 + arow;  // this wave's 16 output cols
    const float* Xb = X + (size_t)b * Nn * Ff;

    f32x4 acc = {0.f, 0.f, 0.f, 0.f};
    const int abase = arow * (Nn*2);
    const int aswz  = (arow & 7) << 4;
    for (int kb = 0; kb < Nn / 32; ++kb) {
        const int mb = kb * 32 + kg * 8;
        f16x8 afrag = *(const f16x8*)(fb + ((abase + mb*2) ^ aswz));
        f16x8 bfrag;
        #pragma unroll
        for (int j = 0; j < 8; ++j)
            bfrag[j] = (_Float16)Xb[(size_t)(mb + j) * Ff + fcol];
        acc = __builtin_amdgcn_mfma_f32_16x16x32_f16(afrag, bfrag, acc, 0, 0, 0);
    }
    __syncthreads();   // all A-frag reads done; inv_rowsum visible

    // normalized G1 tile -> LDS (reuse fus storage, plain layout [16][64])
    float* g1 = (float*)fus;
    #pragma unroll
    for (int i = 0; i < 4; ++i) {
        const int rr = kg * 4 + i;     // C row = (lane>>4)*4 + reg
        g1[rr * Ff + fcol] = acc[i] * inv_rowsum[rr];
    }
    __syncthreads();

    // ================= Phase 3: Dense(64) + tanh ==========================
    const int u = lane;
    const int rbase = wid * 4;
    float o[4];
    float bdu = bdv[u];
    o[0] = o[1] = o[2] = o[3] = bdu;
    for (int f = 0; f < Ff; ++f) {
        float wdv = Wd[f * Uu + u];
        #pragma unroll
        for (int i = 0; i < 4; ++i)
            o[i] += g1[(rbase + i) * Ff + f] * wdv;
    }
    #pragma unroll
    for (int i = 0; i < 4; ++i)
        out[((size_t)b * Nn + n0 + rbase + i) * (size_t)Uu + u] = tanhf(o[i]);
}

extern "C" void kernel_launch(void* const* d_in, const int* in_sizes, int n_in,
                              void* d_out, int out_size, void* d_ws, size_t ws_size,
                              hipStream_t stream) {
    const float* X   = (const float*)d_in[0];  // inputs [8,2048,64]
    const float* Dyn = (const float*)d_in[1];  // Dynamic_L [8,2048,2048]
    const float* Wf  = (const float*)d_in[2];  // W [8,2048,2048,3]
    const float* Geo = (const float*)d_in[3];  // Geo [2048,2048]
    const float* KLm = (const float*)d_in[4];  // KL [2048,2048]
    const float* Wd  = (const float*)d_in[5];  // Wd [64,64]
    const float* bdv = (const float*)d_in[6];  // bd [64]
    float* out = (float*)d_out;

    fused_gcn<<<dim3(Bdim * (Nn / Rr)), dim3(NT), 0, stream>>>(
        X, Dyn, Wf, Geo, KLm, Wd, bdv, out);
}